// Round 12
// baseline (97.564 us; speedup 1.0000x reference)
//
#include <hip/hip_runtime.h>
#include <math.h>

// B=32768, P=16, DC=128, H=256, NB=32, KOUT=97 (theta q padded to 128 = 4 q-tiles of 32)
// R27: 256 blocks x 768 threads (12 waves, 1 block/CU -> 3 waves/SIMD).
// KEY INSIGHT: occupancy was BLOCK-SHAPE-capped, not register-capped. LDS
// 138.75KB -> 1 block/CU; a 512-thread block = 8 waves = 2/SIMD by
// construction. 768 threads = 12 waves = 3/SIMD. Register budget/wave at
// 3/SIMD = ~168 unified; the R23 body WITHOUT cross-pair prefetch peaks at
// ~162 (prefetch cfrag_n/pf/hbp was +60). TLP (3 waves) replaces the
// prefetch's latency hiding. 64 pair-slots/block, wave w takes w, w+12, ...
// HARD LESSONS (do not regress):
//   R18: big live arrays spill -> WRITE_SIZE explodes (0.6MB -> 48MB), slow.
//   R21: empty "edge fence" asm is NOT ordered vs independent asm chains;
//        fences must carry wait states + "+a" dataflow edge.
//   R21/R22: pressure where asm-written AGPR state can spill is FATAL -> NaN.
//   R24: LDS stride mod 32 dwords MUST be 4 (288B = 8 mod 32 -> 2.5x conflicts).
//   R25: 2x-unrolled pair body = I-cache regression.
//   R26: GEMM2 one-chunk delay neutral in isolation.
// All-register dataflow: GEMM1-T (hT = W1T.cT, 32x32x16) -> half-lane exchange ->
// GEMM2-T (thetaT = W2T.hT) -> in-register spline (3 phases, selmask carried).
// R15: ADDITIVE swizzle -> immediate-offset LDS reads (W1S=272, W2S=528).
// R17: lane^32 via v_permlane32_swap_b32; max-free one-exp cum_softmax.
// R20: select-then-softplus; exp2/log2 domain (W2,b2 * log2e staged).
// R23 (94.6us): staged per-tile fences. R27 = R23 body, prefetch-free, 12 waves.
#define NBLK 256
#define NTHR 768
#define NSLOT 64           // pair-slots per block (128 outputs)
#define NWAVE 12

typedef float  f32x4  __attribute__((ext_vector_type(4)));
typedef float  f32x16 __attribute__((ext_vector_type(16)));
typedef __bf16 bf16x8 __attribute__((ext_vector_type(8)));
typedef unsigned int u32x4 __attribute__((ext_vector_type(4)));

// LDS (bytes)
#define W1S 272            // W1T row stride (bf16 [256 j][128 d] + 16B pad; 68dw=4 mod 32)
#define W2S 528            // W2T row stride (bf16 [128 q][256 j] + 16B pad; 132dw=4 mod 32)
#define LDS_W1T 0          // 256*272 = 69632
#define LDS_W2T 69632      // 128*528 = 67584 -> 137216
#define LDS_B1  137216     // f32 [256] -> 1024B
#define LDS_B2  138240     // f32 [128] (97 real + pad) -> 512B
#define LDS_TOTAL 138752

#define L2PIF 0.9189385332046727f
#define AW (1.0f - 32.0f*1e-5f)
#define LOG2E 1.4426950408889634f
#define LN2F  0.6931471805599453f

// ---------------- MFMA wrappers ----------------
// Hazard model (hidden from LLVM by asm, handled by hand):
//   VALU-write -> MFMA-read (srcA/B/C): 2 wait states  -> s_nop 1 variants
//   MFMA(16-pass) D-write -> VALU/accvgpr read: >=18   -> 3x s_nop 7 fence
//     carrying a "+a"/"+v" dataflow edge (sound under ANY scheduling)
//   MFMA -> MFMA same-acc accumulate: 0 (HW-interlocked)
//   ds_read operands: covered by compiler lgkmcnt waits
__device__ __forceinline__ void mfma_v(f32x16& acc, bf16x8 a, bf16x8 b) {      // nop: fresh srcC seed
    asm("s_nop 1\n\tv_mfma_f32_32x32x16_bf16 %0, %1, %2, %0"
        : "+v"(acc) : "v"(a), "v"(b));
}
__device__ __forceinline__ void mfma_v_f(f32x16& acc, bf16x8 a, bf16x8 b) {    // no nop
    asm("v_mfma_f32_32x32x16_bf16 %0, %1, %2, %0"
        : "+v"(acc) : "v"(a), "v"(b));
}
__device__ __forceinline__ void mfma_a_f(f32x16& acc, bf16x8 a, bf16x8 b) {    // no nop
    asm("v_mfma_f32_32x32x16_bf16 %0, %1, %2, %0"
        : "+a"(acc) : "v"(a), "v"(b));
}
__device__ __forceinline__ void mfma_a_n(f32x16& acc, bf16x8 a, bf16x8 b) {    // nop: fresh A/B
    asm("s_nop 1\n\tv_mfma_f32_32x32x16_bf16 %0, %1, %2, %0"
        : "+a"(acc) : "v"(a), "v"(b));
}
__device__ __forceinline__ void mfma_a_init(f32x16& acc, bf16x8 a, bf16x8 b) { // literal-0 srcC, old ops
    asm("v_mfma_f32_32x32x16_bf16 %0, %1, %2, 0"
        : "=a"(acc) : "v"(a), "v"(b));
}
__device__ __forceinline__ void mfma_a_init_n(f32x16& acc, bf16x8 a, bf16x8 b) { // literal-0, fresh A/B
    asm("s_nop 1\n\tv_mfma_f32_32x32x16_bf16 %0, %1, %2, 0"
        : "=a"(acc) : "v"(a), "v"(b));
}
// Full drain fences (24 wait states >= 18 required), dependency-carried.
__device__ __forceinline__ void mfma_fence_va(f32x16& v0, f32x16& a1) {
    asm("s_nop 7\n\ts_nop 7\n\ts_nop 7" : "+v"(v0), "+a"(a1));
}
__device__ __forceinline__ void mfma_fence1(f32x16& a0) {
    asm("s_nop 7\n\ts_nop 7\n\ts_nop 7" : "+a"(a0));
}
__device__ __forceinline__ void mfma_fence2aa(f32x16& a0, f32x16& a1) {
    asm("s_nop 7\n\ts_nop 7\n\ts_nop 7" : "+a"(a0), "+a"(a1));
}

// ---------------- lane^32 primitives via v_permlane32_swap_b32 ----------------
// ISA semantics (CDNA4): pl32swap(A,B): A -> [A_lo | B_lo], B -> [A_hi | B_hi].
__device__ __forceinline__ void pl32swap(unsigned &a, unsigned &b) {
#if __has_builtin(__builtin_amdgcn_permlane32_swap)
    auto r = __builtin_amdgcn_permlane32_swap(a, b, false, false);
    a = (unsigned)r[0]; b = (unsigned)r[1];
#else
    asm("v_permlane32_swap_b32 %0, %1" : "+v"(a), "+v"(b));
#endif
}
__device__ __forceinline__ float sum32(float x) {   // x + shfl_xor(x,32), orient.-immune
    unsigned a = __float_as_uint(x), b = a;
    pl32swap(a, b);
    return __uint_as_float(a) + __uint_as_float(b);
}
__device__ __forceinline__ float part32(float x) {  // shfl_xor(x,32), exact, orient.-immune
    unsigned u = __float_as_uint(x), a = u, b = u;
    pl32swap(a, b);
    return __uint_as_float(a ^ b ^ u);
}

__device__ __forceinline__ float rcpf(float x) {
#if __has_builtin(__builtin_amdgcn_rcpf)
    return __builtin_amdgcn_rcpf(x);
#else
    return 1.f / x;
#endif
}
// 2^x (bare v_exp_f32) and log2(x) (bare v_log_f32)
__device__ __forceinline__ float exp2f_i(float x) {
#if __has_builtin(__builtin_amdgcn_exp2f)
    return __builtin_amdgcn_exp2f(x);
#else
    return __expf(x * LN2F);
#endif
}
__device__ __forceinline__ float log2f_i(float x) {
#if __has_builtin(__builtin_amdgcn_logf)
    return __builtin_amdgcn_logf(x);
#else
    return __logf(x) * LOG2E;
#endif
}
// softplus in log2 domain: input u' = u*log2e, returns softplus(u)/ln2
__device__ __forceinline__ float softplus2(float up) {
    return fmaxf(up, 0.f) + log2f_i(1.f + exp2f_i(-fabsf(up)));
}

template<int CTRL>
__device__ __forceinline__ float dppf(float v) {
    return __int_as_float(__builtin_amdgcn_update_dpp(
        0, __float_as_int(v), CTRL, 0xF, 0xF, false));
}
__device__ __forceinline__ float rorsum16(float x) {   // sum within 16-lane rows
    x += dppf<0x121>(x);
    x += dppf<0x122>(x);
    x += dppf<0x124>(x);
    x += dppf<0x128>(x);
    return x;
}
__device__ __forceinline__ unsigned packbf(float a, float b) {
    unsigned short ua = __builtin_bit_cast(unsigned short, (__bf16)a);
    unsigned short ub = __builtin_bit_cast(unsigned short, (__bf16)b);
    return (unsigned)ua | ((unsigned)ub << 16);
}
__device__ __forceinline__ bf16x8 cvt8(f32x4 a, f32x4 b) {
    bf16x8 r;
    r[0]=(__bf16)a[0]; r[1]=(__bf16)a[1]; r[2]=(__bf16)a[2]; r[3]=(__bf16)a[3];
    r[4]=(__bf16)b[0]; r[5]=(__bf16)b[1]; r[6]=(__bf16)b[2]; r[7]=(__bf16)b[3];
    return r;
}

// softmax+cumsum over 32 values held as lane-pair (q = 8m + 4h + e).
// Inputs tv, bias ALREADY scaled by log2e -> bare v_exp (2^x) is exp(theta+b).
// No max pass (shift-invariant; |theta|~0.1). Exps computed ONCE into a[16],
// overwritten in place by the scaled cumsum. Partner prefixes + bin left-edges
// (pw0) derived algebraically from 4 swap-summed block totals.
__device__ __forceinline__ void cum_softmax(const f32x16& tv, const char* bias,
                                            int h, float hf, float hoff,
                                            float* a, float* pw0)
{
    float bs0, bs1, bs2, bs3;
    #pragma unroll
    for (int m = 0; m < 4; ++m) {
        f32x4 bv = *(const f32x4*)(bias + m*32);
        float e0 = exp2f_i(tv[4*m+0] + bv[0]);
        float e1 = exp2f_i(tv[4*m+1] + bv[1]);
        float e2 = exp2f_i(tv[4*m+2] + bv[2]);
        float e3 = exp2f_i(tv[4*m+3] + bv[3]);
        a[4*m+0] = e0; a[4*m+1] = e1; a[4*m+2] = e2; a[4*m+3] = e3;
        float s = (e0 + e1) + (e2 + e3);
        if (m == 0) bs0 = s; else if (m == 1) bs1 = s;
        else if (m == 2) bs2 = s; else bs3 = s;
    }
    float t0 = sum32(bs0), t1 = sum32(bs1), t2 = sum32(bs2), t3 = sum32(bs3);
    float T1 = t0, T2 = T1 + t1, T3 = T2 + t2, S = T3 + t3;
    float sc = (20.f * AW) * rcpf(S);
    float st0 = hf * (t0 - bs0);
    float st1 = T1 + hf * (t1 - bs1);
    float st2 = T2 + hf * (t2 - bs2);
    float st3 = T3 + hf * (t3 - bs3);
    pw0[0] = fmaf(sc, st0, hoff);
    pw0[1] = fmaf(sc, st1, hoff + 1.6e-3f);
    pw0[2] = fmaf(sc, st2, hoff + 3.2e-3f);
    pw0[3] = fmaf(sc, st3, hoff + 4.8e-3f);
    #pragma unroll
    for (int m = 0; m < 4; ++m) {
        float run = (m == 0) ? st0 : (m == 1) ? st1 : (m == 2) ? st2 : st3;
        #pragma unroll
        for (int e = 0; e < 4; ++e) {
            run += a[4*m+e];
            a[4*m+e] = hoff + fmaf(sc, run, 2.0e-4f*(float)(8*m + e + 1));
        }
    }
    if (h) a[15] = 10.f;   // force cum[32] = right bound exactly
}

__global__ __launch_bounds__(NTHR)
__attribute__((amdgpu_waves_per_eu(3)))
void flow_kernel(const float* __restrict__ x, const float* __restrict__ c,
                 const float* __restrict__ W1, const float* __restrict__ b1,
                 const float* __restrict__ W2, const float* __restrict__ b2,
                 float* __restrict__ out)
{
    extern __shared__ char smem[];
    const int tid  = threadIdx.x;
    const int wave = tid >> 6;
    const int lane = tid & 63;
    const int p    = lane & 31;   // output column = batch-pair row (2 tiles x 16)
    const int h    = lane >> 5;   // k-half
    const float hf   = (float)h;
    const float hoff = h ? (8.0e-4f - 10.f) : -10.f;

    // ---------------- stage weights (once per CU) ----------------
    {
        const f32x4* W1v = (const f32x4*)W1;   // W1 [128][256] f32 -> 8192 f32x4
        for (int f4i = tid; f4i < 8192; f4i += NTHR) {
            int d  = f4i >> 6;
            int j0 = (f4i & 63) << 2;
            f32x4 v = W1v[f4i];
            #pragma unroll
            for (int e = 0; e < 4; ++e) {
                int j = j0 + e;
                *(__bf16*)(smem + LDS_W1T + j*W1S + d*2) = (__bf16)v[e];
            }
        }
        // W2 staged PRE-SCALED by log2e: theta' = theta*log2e out of GEMM2.
        const f32x4* W2v = (const f32x4*)W2;   // W2 [256][97] f32 -> 6208 f32x4
        for (int f4i = tid; f4i < 6208; f4i += NTHR) {
            f32x4 v = W2v[f4i];
            #pragma unroll
            for (int e = 0; e < 4; ++e) {
                int lin = f4i*4 + e;
                int j = lin / 97;
                int q = lin - j*97;
                *(__bf16*)(smem + LDS_W2T + q*W2S + j*2) = (__bf16)(v[e] * LOG2E);
            }
        }
        for (int i = tid; i < 31*256; i += NTHR) {   // zero-pad q rows 97..127
            int q = 97 + (i >> 8);
            int j = i & 255;
            *(__bf16*)(smem + LDS_W2T + q*W2S + j*2) = (__bf16)0.f;
        }
        float* b1s = (float*)(smem + LDS_B1);
        float* b2s = (float*)(smem + LDS_B2);
        if (tid < 256) b1s[tid] = b1[tid];
        if (tid < 128) b2s[tid] = (tid < 97) ? b2[tid] * LOG2E : 0.f;   // scaled
    }
    __syncthreads();

    // loop-invariant per-lane LDS bases (all reads = base + compile-time imm)
    const char* w1b = smem + LDS_W1T + p*W1S + h*16;   // + jt*32*W1S + s*32
    const char* w2b = smem + LDS_W2T + p*W2S + h*16;   // + qt*32*W2S + kc*32
    const char* bb1 = smem + LDS_B1 + h*16;            // + jt*128 + m*32
    const char* bb2 = smem + LDS_B2 + h*16;            // + phase*128 + m*32
    const float b96v = *(const float*)(smem + LDS_B2 + 384);   // b2[96]*log2e

    const int blockBase = blockIdx.x * 128;

    // slot loop: 64 pair-slots per block, strided by 12 waves (waves 0-3: 6, rest: 5)
    for (int slot = wave; slot < NSLOT; slot += NWAVE) {
        const int t0 = blockBase + slot*2;
        const float* crow = c + (size_t)(t0*16 + p)*128 + h*8;

        const float xr_cur = x[(size_t)(t0*16 + p)*4 + 3];

        // load all 16 c-f32x4 up front (transient; g2 dead here), then convert.
        // TLP (3 waves/SIMD) hides the HBM latency — no cross-pair prefetch.
        bf16x8 cfrag[8];
        {
            f32x4 L[16];
            #pragma unroll
            for (int s = 0; s < 8; ++s) {
                L[2*s]   = *(const f32x4*)(crow + s*16);
                L[2*s+1] = *(const f32x4*)(crow + s*16 + 4);
            }
            #pragma unroll
            for (int s = 0; s < 8; ++s)
                cfrag[s] = cvt8(L[2*s], L[2*s+1]);
        }

        f32x16 g2[4];

        __builtin_amdgcn_s_setprio(1);   // favor the MFMA-issuing phase

        // -------- fused GEMM1-T -> exchange -> GEMM2-T, per 32-j tile --------
        #pragma unroll
        for (int jt = 0; jt < 8; ++jt) {
            // GEMM1: chain A (VGPR acc) seeded with bias as srcC; chain B literal-0.
            f32x16 g1a;
            #pragma unroll
            for (int m = 0; m < 4; ++m) {
                f32x4 bv = *(const f32x4*)(bb1 + jt*128 + m*32);
                g1a[4*m+0] = bv[0]; g1a[4*m+1] = bv[1];
                g1a[4*m+2] = bv[2]; g1a[4*m+3] = bv[3];
            }
            f32x16 g1b;
            #pragma unroll
            for (int s = 0; s < 4; ++s) {
                bf16x8 wa0 = *(const bf16x8*)(w1b + jt*32*W1S + s*32);
                bf16x8 wa1 = *(const bf16x8*)(w1b + jt*32*W1S + (s+4)*32);
                if (s == 0) { mfma_v(g1a, wa0, cfrag[0]);        // nop: fresh seed
                              mfma_a_init(g1b, wa1, cfrag[4]); }
                else        { mfma_v_f(g1a, wa0, cfrag[s]);
                              mfma_a_f(g1b, wa1, cfrag[s+4]); }
            }
            mfma_fence_va(g1a, g1b);   // drain before VALU reads
            // merge + relu + pack to bf16 pairs (bias already in g1a)
            unsigned P[8];
            #pragma unroll
            for (int m = 0; m < 4; ++m) {
                float v0 = fmaxf(g1a[4*m+0] + g1b[4*m+0], 0.f);
                float v1 = fmaxf(g1a[4*m+1] + g1b[4*m+1], 0.f);
                float v2 = fmaxf(g1a[4*m+2] + g1b[4*m+2], 0.f);
                float v3 = fmaxf(g1a[4*m+3] + g1b[4*m+3], 0.f);
                P[2*m]   = packbf(v0, v1);
                P[2*m+1] = packbf(v2, v3);
            }
            // two 16-j chunks: half-lane exchange builds hT B-frags.
            // need: fr0=[pa_lo|pc_lo], fr1=[pb_lo|pd_lo], fr2=[pa_hi|pc_hi], fr3=[pb_hi|pd_hi]
            #pragma unroll
            for (int cc = 0; cc < 2; ++cc) {
                unsigned fa = P[4*cc+0], fb = P[4*cc+2];   // (pa, pc)
                pl32swap(fa, fb);                          // fa -> fr0, fb -> fr2
                unsigned fc = P[4*cc+1], fd = P[4*cc+3];   // (pb, pd)
                pl32swap(fc, fd);                          // fc -> fr1, fd -> fr3
                u32x4 fr;
                fr[0] = fa; fr[1] = fc; fr[2] = fb; fr[3] = fd;
                bf16x8 hb = __builtin_bit_cast(bf16x8, fr);
                const int kc = 2*jt + cc;
                // first MFMA per chunk consumes fresh hb -> s_nop 1 variant
                #pragma unroll
                for (int qt = 0; qt < 4; ++qt) {
                    bf16x8 wb = *(const bf16x8*)(w2b + qt*32*W2S + kc*32);
                    if (jt == 0 && cc == 0) {
                        if (qt == 0) mfma_a_init_n(g2[qt], wb, hb);
                        else         mfma_a_init(g2[qt], wb, hb);
                    } else {
                        if (qt == 0) mfma_a_n(g2[qt], wb, hb);
                        else         mfma_a_f(g2[qt], wb, hb);
                    }
                }
            }
        }
        __builtin_amdgcn_s_setprio(0);

        // ------- spline: STAGED fences — each phase waits only its tile -------
        mfma_fence1(g2[0]);
        const float xs = fminf(fmaxf(xr_cur, -10.f), 10.f);
        unsigned selm = 0;
        float a_cw, a_cwp;
        {   // widths (q 0..31) — g2[1..3] tails may drain under this VALU
            float cw[16], pw0[4];
            float acw[4]  = {0.f, 0.f, 0.f, 0.f};
            float acwp[4] = {0.f, 0.f, 0.f, 0.f};
            cum_softmax(g2[0], bb2, h, hf, hoff, cw, pw0);
            #pragma unroll
            for (int r = 0; r < 16; ++r) {
                const int m = r >> 2;
                float pw = (r & 3) ? cw[r-1] : pw0[m];
                bool sel = (xs >= pw) && ((xs < cw[r]) || (h && r == 15));
                float mf = sel ? 1.f : 0.f;
                acw[m]  = fmaf(mf, pw,    acw[m]);
                acwp[m] = fmaf(mf, cw[r], acwp[m]);
                selm |= (sel ? 1u : 0u) << r;
            }
            a_cw  = sum32((acw[0]  + acw[1])  + (acw[2]  + acw[3]));
            a_cwp = sum32((acwp[0] + acwp[1]) + (acwp[2] + acwp[3]));
        }
        mfma_fence1(g2[1]);
        float a_ch, a_chp;
        {   // heights (q 32..63)
            float ch[16], ph0[4];
            float ach[4]  = {0.f, 0.f, 0.f, 0.f};
            float achp[4] = {0.f, 0.f, 0.f, 0.f};
            cum_softmax(g2[1], bb2 + 128, h, hf, hoff, ch, ph0);
            #pragma unroll
            for (int r = 0; r < 16; ++r) {
                const int m = r >> 2;
                float ph = (r & 3) ? ch[r-1] : ph0[m];
                float mf = (float)((selm >> r) & 1u);
                ach[m]  = fmaf(mf, ph,    ach[m]);
                achp[m] = fmaf(mf, ch[r], achp[m]);
            }
            a_ch  = sum32((ach[0]  + ach[1])  + (ach[2]  + ach[3]));
            a_chp = sum32((achp[0] + achp[1]) + (achp[2] + achp[3]));
        }
        mfma_fence2aa(g2[2], g2[3]);
        float a_d0, a_d1;
        {   // derivatives (q 64..96): mask-sum RAW (log2e-scaled) preacts,
            // softplus ONCE per selected scalar (one-hot commutes with
            // elementwise softplus). rv in scaled domain; final fma by ln2.
            float rv[16];
            float ad0[4] = {0.f, 0.f, 0.f, 0.f};
            float ad1[4] = {0.f, 0.f, 0.f, 0.f};
            #pragma unroll
            for (int m = 0; m < 4; ++m) {
                f32x4 bv = *(const f32x4*)(bb2 + 256 + m*32);
                #pragma unroll
                for (int e = 0; e < 4; ++e)
                    rv[4*m+e] = g2[2][4*m+e] + bv[e];
            }
            float d32r = g2[3][0] + b96v;
            float Z[4];
            #pragma unroll
            for (int m = 0; m < 4; ++m) Z[m] = part32(rv[4*m]);
            float Z4 = part32(d32r);
            #pragma unroll
            for (int r = 0; r < 16; ++r) {
                const int m = r >> 2;
                float nd = ((r & 3) < 3) ? rv[r+1] : (h ? ((m < 3) ? Z[m+1] : Z4) : Z[m]);
                float mf = (float)((selm >> r) & 1u);
                ad0[m] = fmaf(mf, rv[r], ad0[m]);
                ad1[m] = fmaf(mf, nd,    ad1[m]);
            }
            float u0 = sum32((ad0[0] + ad0[1]) + (ad0[2] + ad0[3]));
            float u1 = sum32((ad1[0] + ad1[1]) + (ad1[2] + ad1[3]));
            a_d0 = fmaf(LN2F, softplus2(u0), 1e-5f);
            a_d1 = fmaf(LN2F, softplus2(u1), 1e-5f);
        }

        float val;
        if (xr_cur >= -10.f && xr_cur <= 10.f) {
            float in_w  = a_cwp - a_cw;
            float in_h  = a_chp - a_ch;
            float rw    = rcpf(in_w);
            float delta = in_h * rw;
            float tt    = (xs - a_cw) * rw;
            float thom  = tt * (1.f - tt);
            float den   = delta + (a_d0 + a_d1 - 2.f*delta)*thom;
            float rden  = rcpf(den);
            float z     = fmaf(in_h*(delta*tt*tt + a_d0*thom), rden, a_ch);
            float omt   = 1.f - tt;
            float dnum  = delta*delta*(a_d1*tt*tt + 2.f*delta*thom + a_d0*omt*omt);
            float lv    = log2f_i(dnum) - 2.f*log2f_i(den);
            val = fmaf(LN2F, lv, -L2PIF - 0.5f*z*z);
        } else {
            val = -L2PIF - 0.5f*xr_cur*xr_cur;
        }

        // sum 16 rows per tile (lanes 0-15 = tile0, 16-31 = tile1)
        val = rorsum16(val);
        if (lane == 0)  out[t0]     = val;
        if (lane == 16) out[t0 + 1] = val;
    }
}

extern "C" void kernel_launch(void* const* d_in, const int* in_sizes, int n_in,
                              void* d_out, int out_size, void* d_ws, size_t ws_size,
                              hipStream_t stream) {
    (void)in_sizes; (void)n_in; (void)out_size; (void)d_ws; (void)ws_size;
    const float* x  = (const float*)d_in[0];
    const float* c  = (const float*)d_in[1];
    const float* W1 = (const float*)d_in[2];
    const float* b1 = (const float*)d_in[3];
    const float* W2 = (const float*)d_in[4];
    const float* b2 = (const float*)d_in[5];
    float* out = (float*)d_out;

    (void)hipFuncSetAttribute((const void*)flow_kernel,
                              hipFuncAttributeMaxDynamicSharedMemorySize, LDS_TOTAL);

    flow_kernel<<<NBLK, NTHR, LDS_TOTAL, stream>>>(x, c, W1, b1, W2, b2, out);
}

// Round 13
// 94.540 us; speedup vs baseline: 1.0320x; 1.0320x over previous
//
#include <hip/hip_runtime.h>
#include <math.h>

// B=32768, P=16, DC=128, H=256, NB=32, KOUT=97 (theta q padded to 128 = 4 q-tiles of 32)
// 256 blocks x 512 threads (8 waves, 1 block/CU, 2 waves/SIMD).
// FINAL (R28 = R23, the session best at 94.6us; 150.5 -> 94.6 over the session).
// NOTE: LDS = 138.75KB -> 1 block/CU structurally; 2 waves/SIMD is the
// occupancy ceiling for this body (~216 unified regs incl. AGPRs; 3/SIMD
// needs <=168 and the prefetch-free variant that fits lost more to load
// stalls than TLP recovered — R27: 97.6us).
// HARD LESSONS (do not regress):
//   R18: big live arrays spill -> WRITE_SIZE explodes (0.6MB -> 48MB), slow.
//   R21: empty "edge fence" asm is NOT ordered vs independent asm chains;
//        fences must carry wait states + "+a" dataflow edge. Never assume
//        "N instructions in between" provides hazard wait states.
//   R21/R22: pressure where asm-written AGPR state can spill is FATAL
//        (allocator can't insert hazard nops around asm) -> NaN.
//   R24: LDS stride mod 32 dwords MUST be 4 — 288B (8 mod 32) collapsed
//        start banks: conflicts 5.90M -> 14.82M, 94.6 -> 104.2us.
//   R25: 2x-unrolled pair body = I-cache regression (96.2us).
//   R26: GEMM2 one-chunk delay neutral in isolation (95.0us).
//   R27: 12-wave/3-per-SIMD without prefetch = regression (97.6us).
// All-register dataflow: GEMM1-T (hT = W1T.cT, 32x32x16) -> half-lane exchange ->
// GEMM2-T (thetaT = W2T.hT) -> in-register spline (3 phases, selmask carried).
// R15 (150us): ADDITIVE swizzle -> immediate-offset LDS reads (W1S=272, W2S=528).
// R17 (100us): lane^32 via v_permlane32_swap_b32 (A->[A_lo|B_lo], B->[A_hi|B_hi]);
//   max-free one-exp cum_softmax, algebraic partner prefixes; bias-seeded chain A.
// R19 (101us): minimal-nop MFMA; 4-way split select sums.
// R20 (95.7us): select-then-softplus (17->2 softplus); exp2/log2 domain
//   (W2,b2 pre-scaled by log2e at staging).
// R23 (94.6us): staged per-tile fences (width/height/deriv wait only their tile).
#define NBLK 256
#define NTHR 512
#define PAIRS 8

typedef float  f32x4  __attribute__((ext_vector_type(4)));
typedef float  f32x16 __attribute__((ext_vector_type(16)));
typedef __bf16 bf16x8 __attribute__((ext_vector_type(8)));
typedef unsigned int u32x4 __attribute__((ext_vector_type(4)));

// LDS (bytes)
#define W1S 272            // W1T row stride (bf16 [256 j][128 d] + 16B pad; 68dw=4 mod 32)
#define W2S 528            // W2T row stride (bf16 [128 q][256 j] + 16B pad; 132dw=4 mod 32)
#define LDS_W1T 0          // 256*272 = 69632
#define LDS_W2T 69632      // 128*528 = 67584 -> 137216
#define LDS_B1  137216     // f32 [256] -> 1024B
#define LDS_B2  138240     // f32 [128] (97 real + pad) -> 512B
#define LDS_TOTAL 138752

#define L2PIF 0.9189385332046727f
#define AW (1.0f - 32.0f*1e-5f)
#define LOG2E 1.4426950408889634f
#define LN2F  0.6931471805599453f

// ---------------- MFMA wrappers ----------------
// Hazard model (hidden from LLVM by asm, handled by hand):
//   VALU-write -> MFMA-read (srcA/B/C): 2 wait states  -> s_nop 1 variants
//   MFMA(16-pass) D-write -> VALU/accvgpr read: >=18   -> 3x s_nop 7 fence
//     carrying a "+a"/"+v" dataflow edge (sound under ANY scheduling)
//   MFMA -> MFMA same-acc accumulate: 0 (HW-interlocked)
//   ds_read operands: covered by compiler lgkmcnt waits
__device__ __forceinline__ void mfma_v(f32x16& acc, bf16x8 a, bf16x8 b) {      // nop: fresh srcC seed
    asm("s_nop 1\n\tv_mfma_f32_32x32x16_bf16 %0, %1, %2, %0"
        : "+v"(acc) : "v"(a), "v"(b));
}
__device__ __forceinline__ void mfma_v_f(f32x16& acc, bf16x8 a, bf16x8 b) {    // no nop
    asm("v_mfma_f32_32x32x16_bf16 %0, %1, %2, %0"
        : "+v"(acc) : "v"(a), "v"(b));
}
__device__ __forceinline__ void mfma_a_f(f32x16& acc, bf16x8 a, bf16x8 b) {    // no nop
    asm("v_mfma_f32_32x32x16_bf16 %0, %1, %2, %0"
        : "+a"(acc) : "v"(a), "v"(b));
}
__device__ __forceinline__ void mfma_a_n(f32x16& acc, bf16x8 a, bf16x8 b) {    // nop: fresh A/B
    asm("s_nop 1\n\tv_mfma_f32_32x32x16_bf16 %0, %1, %2, %0"
        : "+a"(acc) : "v"(a), "v"(b));
}
__device__ __forceinline__ void mfma_a_init(f32x16& acc, bf16x8 a, bf16x8 b) { // literal-0 srcC, old ops
    asm("v_mfma_f32_32x32x16_bf16 %0, %1, %2, 0"
        : "=a"(acc) : "v"(a), "v"(b));
}
__device__ __forceinline__ void mfma_a_init_n(f32x16& acc, bf16x8 a, bf16x8 b) { // literal-0, fresh A/B
    asm("s_nop 1\n\tv_mfma_f32_32x32x16_bf16 %0, %1, %2, 0"
        : "=a"(acc) : "v"(a), "v"(b));
}
// Full drain fences (24 wait states >= 18 required), dependency-carried.
__device__ __forceinline__ void mfma_fence_va(f32x16& v0, f32x16& a1) {
    asm("s_nop 7\n\ts_nop 7\n\ts_nop 7" : "+v"(v0), "+a"(a1));
}
__device__ __forceinline__ void mfma_fence1(f32x16& a0) {
    asm("s_nop 7\n\ts_nop 7\n\ts_nop 7" : "+a"(a0));
}
__device__ __forceinline__ void mfma_fence2aa(f32x16& a0, f32x16& a1) {
    asm("s_nop 7\n\ts_nop 7\n\ts_nop 7" : "+a"(a0), "+a"(a1));
}

// ---------------- lane^32 primitives via v_permlane32_swap_b32 ----------------
// ISA semantics (CDNA4): pl32swap(A,B): A -> [A_lo | B_lo], B -> [A_hi | B_hi].
__device__ __forceinline__ void pl32swap(unsigned &a, unsigned &b) {
#if __has_builtin(__builtin_amdgcn_permlane32_swap)
    auto r = __builtin_amdgcn_permlane32_swap(a, b, false, false);
    a = (unsigned)r[0]; b = (unsigned)r[1];
#else
    asm("v_permlane32_swap_b32 %0, %1" : "+v"(a), "+v"(b));
#endif
}
__device__ __forceinline__ float sum32(float x) {   // x + shfl_xor(x,32), orient.-immune
    unsigned a = __float_as_uint(x), b = a;
    pl32swap(a, b);
    return __uint_as_float(a) + __uint_as_float(b);
}
__device__ __forceinline__ float part32(float x) {  // shfl_xor(x,32), exact, orient.-immune
    unsigned u = __float_as_uint(x), a = u, b = u;
    pl32swap(a, b);
    return __uint_as_float(a ^ b ^ u);
}

__device__ __forceinline__ float rcpf(float x) {
#if __has_builtin(__builtin_amdgcn_rcpf)
    return __builtin_amdgcn_rcpf(x);
#else
    return 1.f / x;
#endif
}
// 2^x (bare v_exp_f32) and log2(x) (bare v_log_f32)
__device__ __forceinline__ float exp2f_i(float x) {
#if __has_builtin(__builtin_amdgcn_exp2f)
    return __builtin_amdgcn_exp2f(x);
#else
    return __expf(x * LN2F);
#endif
}
__device__ __forceinline__ float log2f_i(float x) {
#if __has_builtin(__builtin_amdgcn_logf)
    return __builtin_amdgcn_logf(x);
#else
    return __logf(x) * LOG2E;
#endif
}
// softplus in log2 domain: input u' = u*log2e, returns softplus(u)/ln2
__device__ __forceinline__ float softplus2(float up) {
    return fmaxf(up, 0.f) + log2f_i(1.f + exp2f_i(-fabsf(up)));
}

template<int CTRL>
__device__ __forceinline__ float dppf(float v) {
    return __int_as_float(__builtin_amdgcn_update_dpp(
        0, __float_as_int(v), CTRL, 0xF, 0xF, false));
}
__device__ __forceinline__ float rorsum16(float x) {   // sum within 16-lane rows
    x += dppf<0x121>(x);
    x += dppf<0x122>(x);
    x += dppf<0x124>(x);
    x += dppf<0x128>(x);
    return x;
}
__device__ __forceinline__ unsigned packbf(float a, float b) {
    unsigned short ua = __builtin_bit_cast(unsigned short, (__bf16)a);
    unsigned short ub = __builtin_bit_cast(unsigned short, (__bf16)b);
    return (unsigned)ua | ((unsigned)ub << 16);
}
__device__ __forceinline__ bf16x8 cvt8(f32x4 a, f32x4 b) {
    bf16x8 r;
    r[0]=(__bf16)a[0]; r[1]=(__bf16)a[1]; r[2]=(__bf16)a[2]; r[3]=(__bf16)a[3];
    r[4]=(__bf16)b[0]; r[5]=(__bf16)b[1]; r[6]=(__bf16)b[2]; r[7]=(__bf16)b[3];
    return r;
}

// softmax+cumsum over 32 values held as lane-pair (q = 8m + 4h + e).
// Inputs tv, bias ALREADY scaled by log2e -> bare v_exp (2^x) is exp(theta+b).
// No max pass (shift-invariant; |theta|~0.1). Exps computed ONCE into a[16],
// overwritten in place by the scaled cumsum. Partner prefixes + bin left-edges
// (pw0) derived algebraically from 4 swap-summed block totals.
__device__ __forceinline__ void cum_softmax(const f32x16& tv, const char* bias,
                                            int h, float hf, float hoff,
                                            float* a, float* pw0)
{
    float bs0, bs1, bs2, bs3;
    #pragma unroll
    for (int m = 0; m < 4; ++m) {
        f32x4 bv = *(const f32x4*)(bias + m*32);
        float e0 = exp2f_i(tv[4*m+0] + bv[0]);
        float e1 = exp2f_i(tv[4*m+1] + bv[1]);
        float e2 = exp2f_i(tv[4*m+2] + bv[2]);
        float e3 = exp2f_i(tv[4*m+3] + bv[3]);
        a[4*m+0] = e0; a[4*m+1] = e1; a[4*m+2] = e2; a[4*m+3] = e3;
        float s = (e0 + e1) + (e2 + e3);
        if (m == 0) bs0 = s; else if (m == 1) bs1 = s;
        else if (m == 2) bs2 = s; else bs3 = s;
    }
    float t0 = sum32(bs0), t1 = sum32(bs1), t2 = sum32(bs2), t3 = sum32(bs3);
    float T1 = t0, T2 = T1 + t1, T3 = T2 + t2, S = T3 + t3;
    float sc = (20.f * AW) * rcpf(S);
    float st0 = hf * (t0 - bs0);
    float st1 = T1 + hf * (t1 - bs1);
    float st2 = T2 + hf * (t2 - bs2);
    float st3 = T3 + hf * (t3 - bs3);
    pw0[0] = fmaf(sc, st0, hoff);
    pw0[1] = fmaf(sc, st1, hoff + 1.6e-3f);
    pw0[2] = fmaf(sc, st2, hoff + 3.2e-3f);
    pw0[3] = fmaf(sc, st3, hoff + 4.8e-3f);
    #pragma unroll
    for (int m = 0; m < 4; ++m) {
        float run = (m == 0) ? st0 : (m == 1) ? st1 : (m == 2) ? st2 : st3;
        #pragma unroll
        for (int e = 0; e < 4; ++e) {
            run += a[4*m+e];
            a[4*m+e] = hoff + fmaf(sc, run, 2.0e-4f*(float)(8*m + e + 1));
        }
    }
    if (h) a[15] = 10.f;   // force cum[32] = right bound exactly
}

__global__ __launch_bounds__(NTHR)
__attribute__((amdgpu_waves_per_eu(2)))
void flow_kernel(const float* __restrict__ x, const float* __restrict__ c,
                 const float* __restrict__ W1, const float* __restrict__ b1,
                 const float* __restrict__ W2, const float* __restrict__ b2,
                 float* __restrict__ out)
{
    extern __shared__ char smem[];
    const int tid  = threadIdx.x;
    const int wave = tid >> 6;
    const int lane = tid & 63;
    const int p    = lane & 31;   // output column = batch-pair row (2 tiles x 16)
    const int h    = lane >> 5;   // k-half
    const float hf   = (float)h;
    const float hoff = h ? (8.0e-4f - 10.f) : -10.f;

    // ---------------- stage weights (once per CU) ----------------
    {
        const f32x4* W1v = (const f32x4*)W1;   // W1 [128][256] f32 -> 8192 f32x4
        for (int it = 0; it < 16; ++it) {
            int f4i = tid + it*NTHR;
            int d  = f4i >> 6;
            int j0 = (f4i & 63) << 2;
            f32x4 v = W1v[f4i];
            #pragma unroll
            for (int e = 0; e < 4; ++e) {
                int j = j0 + e;
                *(__bf16*)(smem + LDS_W1T + j*W1S + d*2) = (__bf16)v[e];
            }
        }
        // W2 staged PRE-SCALED by log2e: theta' = theta*log2e out of GEMM2.
        const f32x4* W2v = (const f32x4*)W2;   // W2 [256][97] f32 -> 6208 f32x4
        for (int f4i = tid; f4i < 6208; f4i += NTHR) {
            f32x4 v = W2v[f4i];
            #pragma unroll
            for (int e = 0; e < 4; ++e) {
                int lin = f4i*4 + e;
                int j = lin / 97;
                int q = lin - j*97;
                *(__bf16*)(smem + LDS_W2T + q*W2S + j*2) = (__bf16)(v[e] * LOG2E);
            }
        }
        for (int i = tid; i < 31*256; i += NTHR) {   // zero-pad q rows 97..127
            int q = 97 + (i >> 8);
            int j = i & 255;
            *(__bf16*)(smem + LDS_W2T + q*W2S + j*2) = (__bf16)0.f;
        }
        float* b1s = (float*)(smem + LDS_B1);
        float* b2s = (float*)(smem + LDS_B2);
        if (tid < 256) b1s[tid] = b1[tid];
        if (tid < 128) b2s[tid] = (tid < 97) ? b2[tid] * LOG2E : 0.f;   // scaled
    }
    __syncthreads();

    // loop-invariant per-lane LDS bases (all reads = base + compile-time imm)
    const char* w1b = smem + LDS_W1T + p*W1S + h*16;   // + jt*32*W1S + s*32
    const char* w2b = smem + LDS_W2T + p*W2S + h*16;   // + qt*32*W2S + kc*32
    const char* bb1 = smem + LDS_B1 + h*16;            // + jt*128 + m*32
    const char* bb2 = smem + LDS_B2 + h*16;            // + phase*128 + m*32
    const float b96v = *(const float*)(smem + LDS_B2 + 384);   // b2[96]*log2e

    const int base = blockIdx.x*128 + wave*16;

    // preload pair 0: c -> bf16 B-frags (convert-at-load), and x
    bf16x8 cfrag[8];
    {
        const float* crow = c + (size_t)(base*16 + p)*128 + h*8;
        #pragma unroll
        for (int s = 0; s < 8; ++s)
            cfrag[s] = cvt8(*(const f32x4*)(crow + s*16),
                            *(const f32x4*)(crow + s*16 + 4));
    }
    float xr = x[(size_t)(base*16 + p)*4 + 3];

    for (int itn = 0; itn < PAIRS; ++itn) {
        const int t0 = base + itn*2;
        // next-pair source row (last pair: re-read current -> harmless, L2-hot)
        const int tn = (itn + 1 < PAIRS) ? (t0 + 2) : t0;
        const float* crow_n = c + (size_t)(tn*16 + p)*128 + h*8;

        f32x16 g2[4];
        f32x4  pf[6];        // rotating 3-slot pending buffer (24 regs)
        bf16x8 cfrag_n[8];   // next pair's converted B-frags

        __builtin_amdgcn_s_setprio(1);   // favor the MFMA-issuing phase

        // -------- fused GEMM1-T -> exchange -> GEMM2-T, per 32-j tile --------
        // prefetch pipeline: issue chunk s=jt (slot jt%3); convert chunk jt-2.
        #pragma unroll
        for (int jt = 0; jt < 8; ++jt) {
            pf[(jt % 3)*2]     = *(const f32x4*)(crow_n + jt*16);
            pf[(jt % 3)*2 + 1] = *(const f32x4*)(crow_n + jt*16 + 4);

            // GEMM1: chain A (VGPR acc) seeded with bias as srcC; chain B literal-0.
            f32x16 g1a;
            #pragma unroll
            for (int m = 0; m < 4; ++m) {
                f32x4 bv = *(const f32x4*)(bb1 + jt*128 + m*32);
                g1a[4*m+0] = bv[0]; g1a[4*m+1] = bv[1];
                g1a[4*m+2] = bv[2]; g1a[4*m+3] = bv[3];
            }
            f32x16 g1b;
            #pragma unroll
            for (int s = 0; s < 4; ++s) {
                bf16x8 wa0 = *(const bf16x8*)(w1b + jt*32*W1S + s*32);
                bf16x8 wa1 = *(const bf16x8*)(w1b + jt*32*W1S + (s+4)*32);
                if (s == 0) { mfma_v(g1a, wa0, cfrag[0]);        // nop: fresh seed
                              mfma_a_init(g1b, wa1, cfrag[4]); }
                else        { mfma_v_f(g1a, wa0, cfrag[s]);
                              mfma_a_f(g1b, wa1, cfrag[s+4]); }
            }
            mfma_fence_va(g1a, g1b);   // drain before VALU reads
            // merge + relu + pack to bf16 pairs (bias already in g1a)
            unsigned P[8];
            #pragma unroll
            for (int m = 0; m < 4; ++m) {
                float v0 = fmaxf(g1a[4*m+0] + g1b[4*m+0], 0.f);
                float v1 = fmaxf(g1a[4*m+1] + g1b[4*m+1], 0.f);
                float v2 = fmaxf(g1a[4*m+2] + g1b[4*m+2], 0.f);
                float v3 = fmaxf(g1a[4*m+3] + g1b[4*m+3], 0.f);
                P[2*m]   = packbf(v0, v1);
                P[2*m+1] = packbf(v2, v3);
            }
            // two 16-j chunks: half-lane exchange builds hT B-frags.
            // need: fr0=[pa_lo|pc_lo], fr1=[pb_lo|pd_lo], fr2=[pa_hi|pc_hi], fr3=[pb_hi|pd_hi]
            #pragma unroll
            for (int cc = 0; cc < 2; ++cc) {
                unsigned fa = P[4*cc+0], fb = P[4*cc+2];   // (pa, pc)
                pl32swap(fa, fb);                          // fa -> fr0, fb -> fr2
                unsigned fc = P[4*cc+1], fd = P[4*cc+3];   // (pb, pd)
                pl32swap(fc, fd);                          // fc -> fr1, fd -> fr3
                u32x4 fr;
                fr[0] = fa; fr[1] = fc; fr[2] = fb; fr[3] = fd;
                bf16x8 hb = __builtin_bit_cast(bf16x8, fr);
                const int kc = 2*jt + cc;
                // first MFMA per chunk consumes fresh hb -> s_nop 1 variant;
                // the rest are >=3 instr slots past the permlane writes.
                #pragma unroll
                for (int qt = 0; qt < 4; ++qt) {
                    bf16x8 wb = *(const bf16x8*)(w2b + qt*32*W2S + kc*32);
                    if (jt == 0 && cc == 0) {
                        if (qt == 0) mfma_a_init_n(g2[qt], wb, hb);
                        else         mfma_a_init(g2[qt], wb, hb);
                    } else {
                        if (qt == 0) mfma_a_n(g2[qt], wb, hb);
                        else         mfma_a_f(g2[qt], wb, hb);
                    }
                }
            }
            // convert chunk jt-2 (loads issued 2 jt-iterations ago)
            if (jt >= 2) {
                const int s = jt - 2;
                cfrag_n[s] = cvt8(pf[(s % 3)*2], pf[(s % 3)*2 + 1]);
            }
        }
        __builtin_amdgcn_s_setprio(0);

        // drain chunks 6,7 (dead on last pair) + next x: fills drain window
        if (itn + 1 < PAIRS) {
            cfrag_n[6] = cvt8(pf[(6 % 3)*2], pf[(6 % 3)*2 + 1]);
            cfrag_n[7] = cvt8(pf[(7 % 3)*2], pf[(7 % 3)*2 + 1]);
        }
        const float xr_cur = xr;
        float xn = x[(size_t)(tn*16 + p)*4 + 3];

        // ------- spline: STAGED fences — each phase waits only its tile -------
        mfma_fence1(g2[0]);
        const float xs = fminf(fmaxf(xr_cur, -10.f), 10.f);
        unsigned selm = 0;
        float a_cw, a_cwp;
        {   // widths (q 0..31) — g2[1..3] tails may drain under this VALU
            float cw[16], pw0[4];
            float acw[4]  = {0.f, 0.f, 0.f, 0.f};
            float acwp[4] = {0.f, 0.f, 0.f, 0.f};
            cum_softmax(g2[0], bb2, h, hf, hoff, cw, pw0);
            #pragma unroll
            for (int r = 0; r < 16; ++r) {
                const int m = r >> 2;
                float pw = (r & 3) ? cw[r-1] : pw0[m];
                bool sel = (xs >= pw) && ((xs < cw[r]) || (h && r == 15));
                float mf = sel ? 1.f : 0.f;
                acw[m]  = fmaf(mf, pw,    acw[m]);
                acwp[m] = fmaf(mf, cw[r], acwp[m]);
                selm |= (sel ? 1u : 0u) << r;
            }
            a_cw  = sum32((acw[0]  + acw[1])  + (acw[2]  + acw[3]));
            a_cwp = sum32((acwp[0] + acwp[1]) + (acwp[2] + acwp[3]));
        }
        mfma_fence1(g2[1]);
        float a_ch, a_chp;
        {   // heights (q 32..63)
            float ch[16], ph0[4];
            float ach[4]  = {0.f, 0.f, 0.f, 0.f};
            float achp[4] = {0.f, 0.f, 0.f, 0.f};
            cum_softmax(g2[1], bb2 + 128, h, hf, hoff, ch, ph0);
            #pragma unroll
            for (int r = 0; r < 16; ++r) {
                const int m = r >> 2;
                float ph = (r & 3) ? ch[r-1] : ph0[m];
                float mf = (float)((selm >> r) & 1u);
                ach[m]  = fmaf(mf, ph,    ach[m]);
                achp[m] = fmaf(mf, ch[r], achp[m]);
            }
            a_ch  = sum32((ach[0]  + ach[1])  + (ach[2]  + ach[3]));
            a_chp = sum32((achp[0] + achp[1]) + (achp[2] + achp[3]));
        }
        mfma_fence2aa(g2[2], g2[3]);
        float a_d0, a_d1;
        {   // derivatives (q 64..96): mask-sum RAW (log2e-scaled) preacts,
            // softplus ONCE per selected scalar (one-hot commutes with
            // elementwise softplus). rv in scaled domain; final fma by ln2.
            float rv[16];
            float ad0[4] = {0.f, 0.f, 0.f, 0.f};
            float ad1[4] = {0.f, 0.f, 0.f, 0.f};
            #pragma unroll
            for (int m = 0; m < 4; ++m) {
                f32x4 bv = *(const f32x4*)(bb2 + 256 + m*32);
                #pragma unroll
                for (int e = 0; e < 4; ++e)
                    rv[4*m+e] = g2[2][4*m+e] + bv[e];
            }
            float d32r = g2[3][0] + b96v;
            float Z[4];
            #pragma unroll
            for (int m = 0; m < 4; ++m) Z[m] = part32(rv[4*m]);
            float Z4 = part32(d32r);
            #pragma unroll
            for (int r = 0; r < 16; ++r) {
                const int m = r >> 2;
                float nd = ((r & 3) < 3) ? rv[r+1] : (h ? ((m < 3) ? Z[m+1] : Z4) : Z[m]);
                float mf = (float)((selm >> r) & 1u);
                ad0[m] = fmaf(mf, rv[r], ad0[m]);
                ad1[m] = fmaf(mf, nd,    ad1[m]);
            }
            float u0 = sum32((ad0[0] + ad0[1]) + (ad0[2] + ad0[3]));
            float u1 = sum32((ad1[0] + ad1[1]) + (ad1[2] + ad1[3]));
            a_d0 = fmaf(LN2F, softplus2(u0), 1e-5f);
            a_d1 = fmaf(LN2F, softplus2(u1), 1e-5f);
        }

        float val;
        if (xr_cur >= -10.f && xr_cur <= 10.f) {
            float in_w  = a_cwp - a_cw;
            float in_h  = a_chp - a_ch;
            float rw    = rcpf(in_w);
            float delta = in_h * rw;
            float tt    = (xs - a_cw) * rw;
            float thom  = tt * (1.f - tt);
            float den   = delta + (a_d0 + a_d1 - 2.f*delta)*thom;
            float rden  = rcpf(den);
            float z     = fmaf(in_h*(delta*tt*tt + a_d0*thom), rden, a_ch);
            float omt   = 1.f - tt;
            float dnum  = delta*delta*(a_d1*tt*tt + 2.f*delta*thom + a_d0*omt*omt);
            float lv    = log2f_i(dnum) - 2.f*log2f_i(den);
            val = fmaf(LN2F, lv, -L2PIF - 0.5f*z*z);
        } else {
            val = -L2PIF - 0.5f*xr_cur*xr_cur;
        }

        // sum 16 rows per tile (lanes 0-15 = tile0, 16-31 = tile1)
        val = rorsum16(val);
        if (lane == 0)  out[t0]     = val;
        if (lane == 16) out[t0 + 1] = val;

        // rotate prefetched state in (dead on last pair)
        xr = xn;
        if (itn + 1 < PAIRS) {
            #pragma unroll
            for (int s = 0; s < 8; ++s) cfrag[s] = cfrag_n[s];
        }
    }
}

extern "C" void kernel_launch(void* const* d_in, const int* in_sizes, int n_in,
                              void* d_out, int out_size, void* d_ws, size_t ws_size,
                              hipStream_t stream) {
    (void)in_sizes; (void)n_in; (void)out_size; (void)d_ws; (void)ws_size;
    const float* x  = (const float*)d_in[0];
    const float* c  = (const float*)d_in[1];
    const float* W1 = (const float*)d_in[2];
    const float* b1 = (const float*)d_in[3];
    const float* W2 = (const float*)d_in[4];
    const float* b2 = (const float*)d_in[5];
    float* out = (float*)d_out;

    (void)hipFuncSetAttribute((const void*)flow_kernel,
                              hipFuncAttributeMaxDynamicSharedMemorySize, LDS_TOTAL);

    flow_kernel<<<NBLK, NTHR, LDS_TOTAL, stream>>>(x, c, W1, b1, W2, b2, out);
}